// Round 3
// baseline (104.342 us; speedup 1.0000x reference)
//
#include <hip/hip_runtime.h>
#include <math.h>

// Problem constants (from reference setup_inputs)
static constexpr int B_ = 32;    // batch
static constexpr int T_ = 336;   // time
static constexpr int C_ = 7;     // channels (m)
static constexpr int N_ = 5;     // shapelets per bank
static constexpr int PB = 140;   // 4 banks * 35 cols per batch row
// d_out layout: out[32*10] | dists[32*140] | probs[32*140] | loss[1]
static constexpr int DIST_OFF = 320;
static constexpr int PROB_OFF = 320 + 4480;   // 4800
static constexpr int LOSS_OFF = 9280;

// Per-bank distance scan: all N_=5 shapelets at once. xs[t+j] is one LDS read
// reused 5x; w accesses are wave-uniform (j loop counter + block-uniform m)
// -> scalar loads, off the LDS/VMEM vector pipes.
template <int L>
__device__ __forceinline__ void bank_body(const float* __restrict__ xs,
                                          const float* __restrict__ w,
                                          int m, int slot0,
                                          unsigned* __restrict__ dminS)
{
    constexpr int TT = T_ - L + 1;
    const int tid  = threadIdx.x;
    const int lane = tid & 63;

    const float* __restrict__ w0 = w + (0 * C_ + m) * L;
    const float* __restrict__ w1 = w + (1 * C_ + m) * L;
    const float* __restrict__ w2 = w + (2 * C_ + m) * L;
    const float* __restrict__ w3 = w + (3 * C_ + m) * L;
    const float* __restrict__ w4 = w + (4 * C_ + m) * L;

    float b0 = INFINITY, b1 = INFINITY, b2 = INFINITY, b3 = INFINITY, b4 = INFINITY;
    for (int t0 = tid; t0 < TT; t0 += 256) {
        float a0 = 0.f, a1 = 0.f, a2 = 0.f, a3 = 0.f, a4 = 0.f;
        #pragma unroll 4
        for (int j = 0; j < L; ++j) {
            const float xv = xs[t0 + j];          // 1 LDS read, reused 5x
            a0 += fabsf(xv - w0[j]);
            a1 += fabsf(xv - w1[j]);
            a2 += fabsf(xv - w2[j]);
            a3 += fabsf(xv - w3[j]);
            a4 += fabsf(xv - w4[j]);
        }
        b0 = fminf(b0, a0); b1 = fminf(b1, a1); b2 = fminf(b2, a2);
        b3 = fminf(b3, a3); b4 = fminf(b4, a4);
    }
    #pragma unroll
    for (int off = 32; off; off >>= 1) {
        b0 = fminf(b0, __shfl_down(b0, off, 64));
        b1 = fminf(b1, __shfl_down(b1, off, 64));
        b2 = fminf(b2, __shfl_down(b2, off, 64));
        b3 = fminf(b3, __shfl_down(b3, off, 64));
        b4 = fminf(b4, __shfl_down(b4, off, 64));
    }
    if (lane == 0) {   // non-negative floats: uint order == float order
        atomicMin(&dminS[slot0 + 0], __float_as_uint(b0));
        atomicMin(&dminS[slot0 + 1], __float_as_uint(b1));
        atomicMin(&dminS[slot0 + 2], __float_as_uint(b2));
        atomicMin(&dminS[slot0 + 3], __float_as_uint(b3));
        atomicMin(&dminS[slot0 + 4], __float_as_uint(b4));
    }
}

// One block per (b, m): all 4 banks, all 5 shapelets. Perfectly balanced grid
// (224 identical blocks), channel normalized exactly once, output GEMV fused
// via atomicAdd into zeroed out[0:320].
__global__ __launch_bounds__(256)
void k_fused(const float* __restrict__ x,
             const float* __restrict__ w0, const float* __restrict__ w1,
             const float* __restrict__ w2, const float* __restrict__ w3,
             const float* __restrict__ W_out,
             float* __restrict__ out)
{
    __shared__ float    xs[T_];
    __shared__ float    red[8];
    __shared__ float    lred[4];
    __shared__ unsigned dminS[20];
    __shared__ float    pS[20];

    const int bid  = blockIdx.x;      // 224 = 32 * 7
    const int b    = bid / C_;
    const int m    = bid % C_;
    const int tid  = threadIdx.x;
    const int lane = tid & 63;
    const int wv   = tid >> 6;

    // ---- load channel row: x[b, t, m], stride C_ ----
    const float* __restrict__ xb = x + (size_t)b * T_ * C_ + m;
    for (int t = tid; t < T_; t += 256) xs[t] = xb[(size_t)t * C_];
    if (tid < 20) dminS[tid] = 0x7F800000u;   // +inf bits
    __syncthreads();

    // ---- two-pass normalize (ddof=1) ----
    float s = 0.f;
    for (int t = tid; t < T_; t += 256) s += xs[t];
    #pragma unroll
    for (int off = 32; off; off >>= 1) s += __shfl_down(s, off, 64);
    if (lane == 0) red[wv] = s;
    __syncthreads();
    const float mu = (red[0] + red[1] + red[2] + red[3]) / (float)T_;

    float q = 0.f;
    for (int t = tid; t < T_; t += 256) { float d = xs[t] - mu; q += d * d; }
    #pragma unroll
    for (int off = 32; off; off >>= 1) q += __shfl_down(q, off, 64);
    if (lane == 0) red[4 + wv] = q;
    __syncthreads();
    const float sd  = sqrtf((red[4] + red[5] + red[6] + red[7]) / (float)(T_ - 1));
    const float inv = 1.f / (sd + 1e-8f);
    for (int t = tid; t < T_; t += 256) xs[t] = (xs[t] - mu) * inv;
    __syncthreads();

    // ---- all 4 banks ----
    bank_body<34 >(xs, w0, m, 0,  dminS);
    bank_body<68 >(xs, w1, m, 5,  dminS);
    bank_body<101>(xs, w2, m, 10, dminS);
    bank_body<168>(xs, w3, m, 15, dminS);
    __syncthreads();

    // ---- epilogue: dists/probs + fused GEMV contribution ----
    if (tid < 20) {
        const int bank = tid / 5, n = tid % 5;
        const int l = (bank == 0) ? 34 : (bank == 1) ? 68 : (bank == 2) ? 101 : 168;
        const float d = __uint_as_float(dminS[tid]) / (float)l;  // sum -> mean
        const float p = expf(-d * d);                            // EPS_GATE = 1.0
        const int col = bank * 35 + n * C_ + m;
        out[DIST_OFF + b * PB + col] = d;
        out[PROB_OFF + b * PB + col] = p;
        pS[tid] = p;
    }
    __syncthreads();
    if (tid < 10) {   // k = tid: out[b,k] += sum over this block's 20 columns
        float acc = 0.f;
        const float* __restrict__ wk = W_out + tid * PB;
        #pragma unroll
        for (int i = 0; i < 20; ++i) {
            const int col = (i / 5) * 35 + (i % 5) * C_ + m;
            acc += pS[i] * wk[col];
        }
        atomicAdd(&out[b * 10 + tid], acc);
    }

    // ---- loss (block 0 only): 0.1 * mean|W_out| over 1400 elems ----
    if (bid == 0) {
        float ls = 0.f;
        for (int j = tid; j < 1400; j += 256) ls += fabsf(W_out[j]);
        #pragma unroll
        for (int off = 32; off; off >>= 1) ls += __shfl_down(ls, off, 64);
        if (lane == 0) lred[wv] = ls;
        __syncthreads();
        if (tid == 0)
            out[LOSS_OFF] = 0.1f * (lred[0] + lred[1] + lred[2] + lred[3]) / 1400.0f;
    }
}

extern "C" void kernel_launch(void* const* d_in, const int* in_sizes, int n_in,
                              void* d_out, int out_size, void* d_ws, size_t ws_size,
                              hipStream_t stream)
{
    const float* x     = (const float*)d_in[0];
    const float* w0    = (const float*)d_in[1];
    const float* w1    = (const float*)d_in[2];
    const float* w2    = (const float*)d_in[3];
    const float* w3    = (const float*)d_in[4];
    const float* W_out = (const float*)d_in[5];
    float* out = (float*)d_out;

    // zero the fused-GEMV accumulator region out[0:320]
    hipMemsetAsync(out, 0, 320 * sizeof(float), stream);
    hipLaunchKernelGGL(k_fused, dim3(B_ * C_), dim3(256), 0, stream,
                       x, w0, w1, w2, w3, W_out, out);
}